// Round 1
// baseline (2362.990 us; speedup 1.0000x reference)
//
#include <hip/hip_runtime.h>
#include <hip/hip_bf16.h>

#define HEADS 4
#define CH 64
#define NEG 0.2f
#define LN_EPS 1e-5f

typedef unsigned int u32;
typedef unsigned short u16;

__device__ __forceinline__ float bflo(u32 u) { return __uint_as_float(u << 16); }
__device__ __forceinline__ float bfhi(u32 u) { return __uint_as_float(u & 0xffff0000u); }
__device__ __forceinline__ u16 f2bf(float f) {
    u32 u = __float_as_uint(f);
    u32 r = u + 0x7fffu + ((u >> 16) & 1u);
    return (u16)(r >> 16);
}

// ---------------- CSR build ----------------
__global__ void k_init_cursor(int* cursor, int n) {
    int i = blockIdx.x * blockDim.x + threadIdx.x;
    if (i < n) cursor[i] = 1;  // self loop
}

__global__ void k_count(const int* __restrict__ dst, int* cursor, int E) {
    int stride = gridDim.x * blockDim.x;
    for (int e = blockIdx.x * blockDim.x + threadIdx.x; e < E; e += stride)
        atomicAdd(&cursor[dst[e]], 1);
}

__global__ void k_blocksum(const int* __restrict__ cnt, int* bsum, int n) {
    __shared__ int sh[256];
    int i = blockIdx.x * 256 + threadIdx.x;
    int v = (i < n) ? cnt[i] : 0;
    sh[threadIdx.x] = v;
    __syncthreads();
    for (int off = 128; off; off >>= 1) {
        if (threadIdx.x < off) sh[threadIdx.x] += sh[threadIdx.x + off];
        __syncthreads();
    }
    if (threadIdx.x == 0) bsum[blockIdx.x] = sh[0];
}

__global__ void k_scan_bsum(const int* __restrict__ bsum, int* boff, int nb) {
    __shared__ int sh[1024];
    int t = threadIdx.x;
    int v = (t < nb) ? bsum[t] : 0;
    sh[t] = v;
    __syncthreads();
    for (int off = 1; off < 1024; off <<= 1) {
        int a = (t >= off) ? sh[t - off] : 0;
        __syncthreads();
        sh[t] += a;
        __syncthreads();
    }
    if (t < nb) boff[t] = sh[t] - v;  // exclusive
}

__global__ void k_make_ptr(const int* cnt, const int* __restrict__ boff,
                           int* rowptr, int* cursor, int n) {
    __shared__ int sh[256];
    int t = threadIdx.x;
    int i = blockIdx.x * 256 + t;
    int v = (i < n) ? cnt[i] : 0;
    sh[t] = v;
    __syncthreads();
    for (int off = 1; off < 256; off <<= 1) {
        int a = (t >= off) ? sh[t - off] : 0;
        __syncthreads();
        sh[t] += a;
        __syncthreads();
    }
    int incl = sh[t] + boff[blockIdx.x];
    if (i < n) {
        rowptr[i + 1] = incl;
        cursor[i] = incl - v;
    }
    if (i == 0) rowptr[0] = 0;
}

__global__ void k_fill(const int* __restrict__ src, const int* __restrict__ dst,
                       int* cursor, int* col_src, int* col_dst, int E, int n) {
    int stride = gridDim.x * blockDim.x;
    int total = E + n;
    for (int idx = blockIdx.x * blockDim.x + threadIdx.x; idx < total; idx += stride) {
        int s, d;
        if (idx < E) { s = src[idx]; d = dst[idx]; }
        else { s = d = idx - E; }
        int pos = atomicAdd(&cursor[d], 1);
        col_src[pos] = s;
        col_dst[pos] = d;
    }
}

// ---------------- per-layer kernels ----------------
// xl = bf16(x @ Wl), xr = bf16(x @ Wr).  x:[n,64], W:[64,256]
#define GR 16
__global__ void k_gemm2(const float* __restrict__ x, const float* __restrict__ Wl,
                        const float* __restrict__ Wr, u16* __restrict__ xl,
                        u16* __restrict__ xr, int n) {
    __shared__ float xs[GR][64];
    int r0 = blockIdx.x * GR;
    int t = threadIdx.x;  // 0..255 = output col
    for (int idx = t; idx < GR * 64; idx += 256) {
        int r = idx >> 6, k = idx & 63;
        int rg = r0 + r;
        xs[r][k] = (rg < n) ? x[(size_t)rg * 64 + k] : 0.f;
    }
    __syncthreads();
    float accl[GR], accr[GR];
#pragma unroll
    for (int r = 0; r < GR; ++r) { accl[r] = 0.f; accr[r] = 0.f; }
    for (int k = 0; k < 64; ++k) {
        float wl = Wl[k * 256 + t];
        float wr = Wr[k * 256 + t];
#pragma unroll
        for (int r = 0; r < GR; ++r) {
            accl[r] = fmaf(xs[r][k], wl, accl[r]);
            accr[r] = fmaf(xs[r][k], wr, accr[r]);
        }
    }
    for (int r = 0; r < GR; ++r) {
        int rg = r0 + r;
        if (rg < n) {
            xl[(size_t)rg * 256 + t] = f2bf(accl[r]);
            xr[(size_t)rg * 256 + t] = f2bf(accr[r]);
        }
    }
}

// logits[h*E2 + j] = sum_c att[h,c] * lrelu(xl[src,h,c] + xr[dst,h,c])
__global__ void k_logits(const u16* __restrict__ xl, const u16* __restrict__ xr,
                         const int* __restrict__ col_src, const int* __restrict__ col_dst,
                         const float* __restrict__ att, float* __restrict__ logits, int E2) {
    __shared__ float a_s[256];
    a_s[threadIdx.x] = att[threadIdx.x];
    __syncthreads();
    int j = blockIdx.x * 256 + threadIdx.x;
    if (j >= E2) return;
    int s = col_src[j], d = col_dst[j];
    const uint4* pl = (const uint4*)(xl + (size_t)s * 256);
    const uint4* pr = (const uint4*)(xr + (size_t)d * 256);
    float acc[4] = {0.f, 0.f, 0.f, 0.f};
#pragma unroll
    for (int ch = 0; ch < 32; ++ch) {
        uint4 va = pl[ch];
        uint4 vb = pr[ch];
        const int h = ch >> 3;
        const int c0 = (ch & 7) * 8;
        u32 aa[4] = {va.x, va.y, va.z, va.w};
        u32 bb[4] = {vb.x, vb.y, vb.z, vb.w};
#pragma unroll
        for (int q = 0; q < 4; ++q) {
            float v0 = bflo(aa[q]) + bflo(bb[q]);
            float v1 = bfhi(aa[q]) + bfhi(bb[q]);
            float l0 = fmaxf(v0, NEG * v0);
            float l1 = fmaxf(v1, NEG * v1);
            acc[h] = fmaf(a_s[h * 64 + c0 + 2 * q], l0, acc[h]);
            acc[h] = fmaf(a_s[h * 64 + c0 + 2 * q + 1], l1, acc[h]);
        }
    }
#pragma unroll
    for (int h = 0; h < 4; ++h) logits[(size_t)h * E2 + j] = acc[h];
}

// one wave per node: softmax over incoming edges + weighted aggregation + head mean
__global__ void k_aggregate(const float* __restrict__ logits, const int* __restrict__ rowptr,
                            const int* __restrict__ col_src, const u16* __restrict__ xl,
                            const float* __restrict__ bias, float* __restrict__ y,
                            int n, int E2) {
    int node = blockIdx.x * 4 + (threadIdx.x >> 6);
    int lane = threadIdx.x & 63;
    if (node >= n) return;
    int start = rowptr[node], end = rowptr[node + 1];
    float yv = 0.f;
    for (int h = 0; h < HEADS; ++h) {
        const float* lg = logits + (size_t)h * E2;
        float m = -1e30f;
        for (int j = start + lane; j < end; j += 64) m = fmaxf(m, lg[j]);
#pragma unroll
        for (int off = 32; off; off >>= 1) m = fmaxf(m, __shfl_xor(m, off, 64));
        float denom = 0.f, acc = 0.f;
        for (int base = start; base < end; base += 64) {
            int j = base + lane;
            float ex = 0.f;
            int s = 0;
            if (j < end) { ex = expf(lg[j] - m); s = col_src[j]; }
            denom += ex;
            int cnt = min(64, end - base);
            for (int e = 0; e < cnt; ++e) {
                float exe = __shfl(ex, e, 64);
                int se = __shfl(s, e, 64);
                float xv = bflo((u32)xl[(size_t)se * 256 + h * 64 + lane]);
                acc = fmaf(exe, xv, acc);
            }
        }
#pragma unroll
        for (int off = 32; off; off >>= 1) denom += __shfl_xor(denom, off, 64);
        yv += acc / (denom + 1e-16f);
    }
    y[(size_t)node * 64 + lane] = yv * 0.25f + bias[lane];
}

// ---------------- LayerNorm (graph mode: stats over ALL n*64 values) ----------------
__global__ void k_ln_reduce(const float* __restrict__ y, double* __restrict__ part, int n) {
    double s = 0.0, ss = 0.0;
    int stride = gridDim.x * blockDim.x;
    for (int i = blockIdx.x * blockDim.x + threadIdx.x; i < n; i += stride) {
        double v = (double)y[i];
        s += v;
        ss = fma(v, v, ss);
    }
    __shared__ double shs[256], shss[256];
    int t = threadIdx.x;
    shs[t] = s; shss[t] = ss;
    __syncthreads();
    for (int off = 128; off; off >>= 1) {
        if (t < off) { shs[t] += shs[t + off]; shss[t] += shss[t + off]; }
        __syncthreads();
    }
    if (t == 0) { part[blockIdx.x * 2] = shs[0]; part[blockIdx.x * 2 + 1] = shss[0]; }
}

__global__ void k_ln_final(const double* __restrict__ part, float* musig, int nb, int n) {
    double s = 0.0, ss = 0.0;
    for (int i = threadIdx.x; i < nb; i += blockDim.x) { s += part[i * 2]; ss += part[i * 2 + 1]; }
    __shared__ double shs[512], shss[512];
    shs[threadIdx.x] = s; shss[threadIdx.x] = ss;
    __syncthreads();
    for (int off = 256; off; off >>= 1) {
        if (threadIdx.x < off) { shs[threadIdx.x] += shs[threadIdx.x + off]; shss[threadIdx.x] += shss[threadIdx.x + off]; }
        __syncthreads();
    }
    if (threadIdx.x == 0) {
        double mu = shs[0] / n;
        double var = shss[0] / n - mu * mu;
        musig[0] = (float)mu;
        musig[1] = (float)(1.0 / sqrt(var + (double)LN_EPS));
    }
}

__global__ void k_ln_apply(const float* __restrict__ y, const float* __restrict__ musig,
                           const float* __restrict__ w, const float* __restrict__ b,
                           float* __restrict__ out, int n64) {
    float mu = musig[0], rs = musig[1];
    int stride = gridDim.x * blockDim.x;
    for (int i = blockIdx.x * blockDim.x + threadIdx.x; i < n64; i += stride) {
        int c = i & 63;
        out[i] = (y[i] - mu) * rs * w[c] + b[c];
    }
}

extern "C" void kernel_launch(void* const* d_in, const int* in_sizes, int n_in,
                              void* d_out, int out_size, void* d_ws, size_t ws_size,
                              hipStream_t stream) {
    const float* x0   = (const float*)d_in[0];
    const int*   ei   = (const int*)d_in[1];
    const float* Wl   = (const float*)d_in[2];
    const float* Wr   = (const float*)d_in[3];
    const float* att  = (const float*)d_in[4];
    const float* bias = (const float*)d_in[5];
    const float* lnw  = (const float*)d_in[6];
    const float* lnb  = (const float*)d_in[7];

    const int n  = in_sizes[0] / 64;
    const int E  = in_sizes[1] / 2;
    const int E2 = E + n;
    const int* srcA = ei;
    const int* dstA = ei + E;

    char* p = (char*)d_ws;
    auto alloc = [&](size_t bytes) -> char* {
        char* r = p;
        p += (bytes + 511) & ~((size_t)511);
        return r;
    };
    u16*    xl      = (u16*)alloc((size_t)n * 256 * 2);
    u16*    xr      = (u16*)alloc((size_t)n * 256 * 2);
    float*  logits  = (float*)alloc((size_t)E2 * 4 * 4);
    float*  xbuf    = (float*)alloc((size_t)n * 64 * 4);
    float*  ybuf    = (float*)alloc((size_t)n * 64 * 4);
    int*    rowptr  = (int*)alloc((size_t)(n + 1) * 4);
    int*    cursor  = (int*)alloc((size_t)n * 4);
    const int nb    = (n + 255) / 256;
    int*    bsum    = (int*)alloc((size_t)nb * 4);
    int*    boff    = (int*)alloc((size_t)nb * 4);
    int*    col_src = (int*)alloc((size_t)E2 * 4);
    int*    col_dst = (int*)alloc((size_t)E2 * 4);
    double* part    = (double*)alloc(512 * 2 * 8);
    float*  musig   = (float*)alloc(16);

    // ---- CSR build (by dst, self loops appended) ----
    k_init_cursor<<<(n + 255) / 256, 256, 0, stream>>>(cursor, n);
    k_count<<<2048, 256, 0, stream>>>(dstA, cursor, E);
    k_blocksum<<<nb, 256, 0, stream>>>(cursor, bsum, n);
    k_scan_bsum<<<1, 1024, 0, stream>>>(bsum, boff, nb);
    k_make_ptr<<<nb, 256, 0, stream>>>(cursor, boff, rowptr, cursor, n);
    k_fill<<<2048, 256, 0, stream>>>(srcA, dstA, cursor, col_src, col_dst, E, n);

    // ---- 3 GATv2 layers ----
    const float* xin = x0;
    for (int l = 0; l < 3; ++l) {
        k_gemm2<<<(n + GR - 1) / GR, 256, 0, stream>>>(
            xin, Wl + (size_t)l * 64 * 256, Wr + (size_t)l * 64 * 256, xl, xr, n);
        k_logits<<<(E2 + 255) / 256, 256, 0, stream>>>(
            xl, xr, col_src, col_dst, att + l * 256, logits, E2);
        k_aggregate<<<(n + 3) / 4, 256, 0, stream>>>(
            logits, rowptr, col_src, xl, bias + l * 64, ybuf, n, E2);
        k_ln_reduce<<<512, 256, 0, stream>>>(ybuf, part, n * 64);
        k_ln_final<<<1, 512, 0, stream>>>(part, musig, 512, n * 64);
        float* outp = (l == 2) ? (float*)d_out : xbuf;
        k_ln_apply<<<2048, 256, 0, stream>>>(ybuf, musig, lnw + l * 64, lnb + l * 64, outp, n * 64);
        xin = xbuf;
    }
}

// Round 2
// 1868.310 us; speedup vs baseline: 1.2648x; 1.2648x over previous
//
#include <hip/hip_runtime.h>
#include <hip/hip_bf16.h>

#define HEADS 4
#define CH 64
#define NEG 0.2f
#define LN_EPS 1e-5f

typedef unsigned int u32;
typedef unsigned short u16;

__device__ __forceinline__ float bflo(u32 u) { return __uint_as_float(u << 16); }
__device__ __forceinline__ float bfhi(u32 u) { return __uint_as_float(u & 0xffff0000u); }
__device__ __forceinline__ u16 f2bf(float f) {
    u32 u = __float_as_uint(f);
    u32 r = u + 0x7fffu + ((u >> 16) & 1u);
    return (u16)(r >> 16);
}

// ---------------- CSR build ----------------
__global__ void k_init_cursor(int* cursor, int n) {
    int i = blockIdx.x * blockDim.x + threadIdx.x;
    if (i < n) cursor[i] = 1;  // self loop
}

__global__ void k_count(const int* __restrict__ dst, int* cursor, int E) {
    int stride = gridDim.x * blockDim.x;
    for (int e = blockIdx.x * blockDim.x + threadIdx.x; e < E; e += stride)
        atomicAdd(&cursor[dst[e]], 1);
}

__global__ void k_blocksum(const int* __restrict__ cnt, int* bsum, int n) {
    __shared__ int sh[256];
    int i = blockIdx.x * 256 + threadIdx.x;
    int v = (i < n) ? cnt[i] : 0;
    sh[threadIdx.x] = v;
    __syncthreads();
    for (int off = 128; off; off >>= 1) {
        if (threadIdx.x < off) sh[threadIdx.x] += sh[threadIdx.x + off];
        __syncthreads();
    }
    if (threadIdx.x == 0) bsum[blockIdx.x] = sh[0];
}

__global__ void k_scan_bsum(const int* __restrict__ bsum, int* boff, int nb) {
    __shared__ int sh[1024];
    int t = threadIdx.x;
    int v = (t < nb) ? bsum[t] : 0;
    sh[t] = v;
    __syncthreads();
    for (int off = 1; off < 1024; off <<= 1) {
        int a = (t >= off) ? sh[t - off] : 0;
        __syncthreads();
        sh[t] += a;
        __syncthreads();
    }
    if (t < nb) boff[t] = sh[t] - v;  // exclusive
}

__global__ void k_make_ptr(const int* cnt, const int* __restrict__ boff,
                           int* rowptr, int* cursor, int n) {
    __shared__ int sh[256];
    int t = threadIdx.x;
    int i = blockIdx.x * 256 + t;
    int v = (i < n) ? cnt[i] : 0;
    sh[t] = v;
    __syncthreads();
    for (int off = 1; off < 256; off <<= 1) {
        int a = (t >= off) ? sh[t - off] : 0;
        __syncthreads();
        sh[t] += a;
        __syncthreads();
    }
    int incl = sh[t] + boff[blockIdx.x];
    if (i < n) {
        rowptr[i + 1] = incl;
        cursor[i] = incl - v;
    }
    if (i == 0) rowptr[0] = 0;
}

__global__ void k_fill(const int* __restrict__ src, const int* __restrict__ dst,
                       int* cursor, int* col_src, int* col_dst, int E, int n) {
    int stride = gridDim.x * blockDim.x;
    int total = E + n;
    for (int idx = blockIdx.x * blockDim.x + threadIdx.x; idx < total; idx += stride) {
        int s, d;
        if (idx < E) { s = src[idx]; d = dst[idx]; }
        else { s = d = idx - E; }
        int pos = atomicAdd(&cursor[d], 1);
        col_src[pos] = s;
        col_dst[pos] = d;
    }
}

// ---------------- per-layer kernels ----------------
// xl = bf16(x @ Wl), xr = bf16(x @ Wr).  x:[n,64], W:[64,256]
#define GR 16
__global__ void k_gemm2(const float* __restrict__ x, const float* __restrict__ Wl,
                        const float* __restrict__ Wr, u16* __restrict__ xl,
                        u16* __restrict__ xr, int n) {
    __shared__ float xs[GR][64];
    int r0 = blockIdx.x * GR;
    int t = threadIdx.x;  // 0..255 = output col
    for (int idx = t; idx < GR * 64; idx += 256) {
        int r = idx >> 6, k = idx & 63;
        int rg = r0 + r;
        xs[r][k] = (rg < n) ? x[(size_t)rg * 64 + k] : 0.f;
    }
    __syncthreads();
    float accl[GR], accr[GR];
#pragma unroll
    for (int r = 0; r < GR; ++r) { accl[r] = 0.f; accr[r] = 0.f; }
    for (int k = 0; k < 64; ++k) {
        float wl = Wl[k * 256 + t];
        float wr = Wr[k * 256 + t];
#pragma unroll
        for (int r = 0; r < GR; ++r) {
            accl[r] = fmaf(xs[r][k], wl, accl[r]);
            accr[r] = fmaf(xs[r][k], wr, accr[r]);
        }
    }
    for (int r = 0; r < GR; ++r) {
        int rg = r0 + r;
        if (rg < n) {
            xl[(size_t)rg * 256 + t] = f2bf(accl[r]);
            xr[(size_t)rg * 256 + t] = f2bf(accr[r]);
        }
    }
}

// logits[h*E2 + j] = sum_c att[h,c] * lrelu(xl[src,h,c] + xr[dst,h,c])
__global__ void k_logits(const u16* __restrict__ xl, const u16* __restrict__ xr,
                         const int* __restrict__ col_src, const int* __restrict__ col_dst,
                         const float* __restrict__ att, float* __restrict__ logits, int E2) {
    __shared__ float a_s[256];
    a_s[threadIdx.x] = att[threadIdx.x];
    __syncthreads();
    int j = blockIdx.x * 256 + threadIdx.x;
    if (j >= E2) return;
    int s = col_src[j], d = col_dst[j];
    const uint4* pl = (const uint4*)(xl + (size_t)s * 256);
    const uint4* pr = (const uint4*)(xr + (size_t)d * 256);
    float acc[4] = {0.f, 0.f, 0.f, 0.f};
#pragma unroll
    for (int ch = 0; ch < 32; ++ch) {
        uint4 va = pl[ch];
        uint4 vb = pr[ch];
        const int h = ch >> 3;
        const int c0 = (ch & 7) * 8;
        u32 aa[4] = {va.x, va.y, va.z, va.w};
        u32 bb[4] = {vb.x, vb.y, vb.z, vb.w};
#pragma unroll
        for (int q = 0; q < 4; ++q) {
            float v0 = bflo(aa[q]) + bflo(bb[q]);
            float v1 = bfhi(aa[q]) + bfhi(bb[q]);
            float l0 = fmaxf(v0, NEG * v0);
            float l1 = fmaxf(v1, NEG * v1);
            acc[h] = fmaf(a_s[h * 64 + c0 + 2 * q], l0, acc[h]);
            acc[h] = fmaf(a_s[h * 64 + c0 + 2 * q + 1], l1, acc[h]);
        }
    }
#pragma unroll
    for (int h = 0; h < 4; ++h) logits[(size_t)h * E2 + j] = acc[h];
}

// wave per node: normalize logits -> alpha in place (all 4 heads)
__global__ void k_softmax(float* __restrict__ logits, const int* __restrict__ rowptr,
                          int n, int E2) {
    int node = blockIdx.x * 4 + (threadIdx.x >> 6);
    int lane = threadIdx.x & 63;
    if (node >= n) return;
    int start = rowptr[node], end = rowptr[node + 1];
#pragma unroll
    for (int h = 0; h < HEADS; ++h) {
        float* lg = logits + (size_t)h * E2;
        float m = -1e30f;
        for (int j = start + lane; j < end; j += 64) m = fmaxf(m, lg[j]);
#pragma unroll
        for (int off = 32; off; off >>= 1) m = fmaxf(m, __shfl_xor(m, off, 64));
        float d = 0.f;
        for (int j = start + lane; j < end; j += 64) d += __expf(lg[j] - m);
#pragma unroll
        for (int off = 32; off; off >>= 1) d += __shfl_xor(d, off, 64);
        float inv = 1.f / (d + 1e-16f);
        for (int j = start + lane; j < end; j += 64) lg[j] = __expf(lg[j] - m) * inv;
    }
}

// block per node, wave h = head h: y[node,c] = mean_h sum_j alpha[h,j]*xl[src_j,h,c] + bias
__global__ void k_spmm(const float* __restrict__ alpha, const int* __restrict__ rowptr,
                       const int* __restrict__ col_src, const u16* __restrict__ xl,
                       const float* __restrict__ bias, float* __restrict__ y,
                       int n, int E2) {
    int node = blockIdx.x;
    int h = threadIdx.x >> 6;
    int lane = threadIdx.x & 63;
    int start = rowptr[node], end = rowptr[node + 1];
    const float* al = alpha + (size_t)h * E2;
    const u16* xh = xl + (size_t)h * 64 + lane;
    float acc = 0.f;
    int j = start;
    for (; j + 4 <= end; j += 4) {
        int s0 = col_src[j], s1 = col_src[j + 1], s2 = col_src[j + 2], s3 = col_src[j + 3];
        float a0 = al[j], a1 = al[j + 1], a2 = al[j + 2], a3 = al[j + 3];
        float x0 = bflo((u32)xh[(size_t)s0 * 256]);
        float x1 = bflo((u32)xh[(size_t)s1 * 256]);
        float x2 = bflo((u32)xh[(size_t)s2 * 256]);
        float x3 = bflo((u32)xh[(size_t)s3 * 256]);
        acc = fmaf(a0, x0, acc);
        acc = fmaf(a1, x1, acc);
        acc = fmaf(a2, x2, acc);
        acc = fmaf(a3, x3, acc);
    }
    for (; j < end; ++j) {
        int s = col_src[j];
        acc = fmaf(al[j], bflo((u32)xh[(size_t)s * 256]), acc);
    }
    __shared__ float sh[HEADS][64];
    sh[h][lane] = acc;
    __syncthreads();
    if (h == 0) {
        float yv = (sh[0][lane] + sh[1][lane] + sh[2][lane] + sh[3][lane]) * 0.25f + bias[lane];
        y[(size_t)node * 64 + lane] = yv;
    }
}

// ---------------- LayerNorm (graph mode: stats over ALL n*64 values) ----------------
__global__ void k_ln_reduce(const float* __restrict__ y, double* __restrict__ part, int n) {
    double s = 0.0, ss = 0.0;
    int stride = gridDim.x * blockDim.x;
    for (int i = blockIdx.x * blockDim.x + threadIdx.x; i < n; i += stride) {
        double v = (double)y[i];
        s += v;
        ss = fma(v, v, ss);
    }
    __shared__ double shs[256], shss[256];
    int t = threadIdx.x;
    shs[t] = s; shss[t] = ss;
    __syncthreads();
    for (int off = 128; off; off >>= 1) {
        if (t < off) { shs[t] += shs[t + off]; shss[t] += shss[t + off]; }
        __syncthreads();
    }
    if (t == 0) { part[blockIdx.x * 2] = shs[0]; part[blockIdx.x * 2 + 1] = shss[0]; }
}

__global__ void k_ln_final(const double* __restrict__ part, float* musig, int nb, int n) {
    double s = 0.0, ss = 0.0;
    for (int i = threadIdx.x; i < nb; i += blockDim.x) { s += part[i * 2]; ss += part[i * 2 + 1]; }
    __shared__ double shs[512], shss[512];
    shs[threadIdx.x] = s; shss[threadIdx.x] = ss;
    __syncthreads();
    for (int off = 256; off; off >>= 1) {
        if (threadIdx.x < off) { shs[threadIdx.x] += shs[threadIdx.x + off]; shss[threadIdx.x] += shss[threadIdx.x + off]; }
        __syncthreads();
    }
    if (threadIdx.x == 0) {
        double mu = shs[0] / n;
        double var = shss[0] / n - mu * mu;
        musig[0] = (float)mu;
        musig[1] = (float)(1.0 / sqrt(var + (double)LN_EPS));
    }
}

__global__ void k_ln_apply(const float* __restrict__ y, const float* __restrict__ musig,
                           const float* __restrict__ w, const float* __restrict__ b,
                           float* __restrict__ out, int n64) {
    float mu = musig[0], rs = musig[1];
    int stride = gridDim.x * blockDim.x;
    for (int i = blockIdx.x * blockDim.x + threadIdx.x; i < n64; i += stride) {
        int c = i & 63;
        out[i] = (y[i] - mu) * rs * w[c] + b[c];
    }
}

extern "C" void kernel_launch(void* const* d_in, const int* in_sizes, int n_in,
                              void* d_out, int out_size, void* d_ws, size_t ws_size,
                              hipStream_t stream) {
    const float* x0   = (const float*)d_in[0];
    const int*   ei   = (const int*)d_in[1];
    const float* Wl   = (const float*)d_in[2];
    const float* Wr   = (const float*)d_in[3];
    const float* att  = (const float*)d_in[4];
    const float* bias = (const float*)d_in[5];
    const float* lnw  = (const float*)d_in[6];
    const float* lnb  = (const float*)d_in[7];

    const int n  = in_sizes[0] / 64;
    const int E  = in_sizes[1] / 2;
    const int E2 = E + n;
    const int* srcA = ei;
    const int* dstA = ei + E;

    char* p = (char*)d_ws;
    auto alloc = [&](size_t bytes) -> char* {
        char* r = p;
        p += (bytes + 511) & ~((size_t)511);
        return r;
    };
    u16*    xl      = (u16*)alloc((size_t)n * 256 * 2);
    u16*    xr      = (u16*)alloc((size_t)n * 256 * 2);
    float*  logits  = (float*)alloc((size_t)E2 * 4 * 4);
    float*  xbuf    = (float*)alloc((size_t)n * 64 * 4);
    float*  ybuf    = (float*)alloc((size_t)n * 64 * 4);
    int*    rowptr  = (int*)alloc((size_t)(n + 1) * 4);
    int*    cursor  = (int*)alloc((size_t)n * 4);
    const int nb    = (n + 255) / 256;
    int*    bsum    = (int*)alloc((size_t)nb * 4);
    int*    boff    = (int*)alloc((size_t)nb * 4);
    int*    col_src = (int*)alloc((size_t)E2 * 4);
    int*    col_dst = (int*)alloc((size_t)E2 * 4);
    double* part    = (double*)alloc(512 * 2 * 8);
    float*  musig   = (float*)alloc(16);

    // ---- CSR build (by dst, self loops appended) ----
    k_init_cursor<<<(n + 255) / 256, 256, 0, stream>>>(cursor, n);
    k_count<<<2048, 256, 0, stream>>>(dstA, cursor, E);
    k_blocksum<<<nb, 256, 0, stream>>>(cursor, bsum, n);
    k_scan_bsum<<<1, 1024, 0, stream>>>(bsum, boff, nb);
    k_make_ptr<<<nb, 256, 0, stream>>>(cursor, boff, rowptr, cursor, n);
    k_fill<<<2048, 256, 0, stream>>>(srcA, dstA, cursor, col_src, col_dst, E, n);

    // ---- 3 GATv2 layers ----
    const float* xin = x0;
    for (int l = 0; l < 3; ++l) {
        k_gemm2<<<(n + GR - 1) / GR, 256, 0, stream>>>(
            xin, Wl + (size_t)l * 64 * 256, Wr + (size_t)l * 64 * 256, xl, xr, n);
        k_logits<<<(E2 + 255) / 256, 256, 0, stream>>>(
            xl, xr, col_src, col_dst, att + l * 256, logits, E2);
        k_softmax<<<(n + 3) / 4, 256, 0, stream>>>(logits, rowptr, n, E2);
        k_spmm<<<n, 256, 0, stream>>>(logits, rowptr, col_src, xl, bias + l * 64, ybuf, n, E2);
        k_ln_reduce<<<512, 256, 0, stream>>>(ybuf, part, n * 64);
        k_ln_final<<<1, 512, 0, stream>>>(part, musig, 512, n * 64);
        float* outp = (l == 2) ? (float*)d_out : xbuf;
        k_ln_apply<<<2048, 256, 0, stream>>>(ybuf, musig, lnw + l * 64, lnb + l * 64, outp, n * 64);
        xin = xbuf;
    }
}

// Round 3
// 1250.431 us; speedup vs baseline: 1.8897x; 1.4941x over previous
//
#include <hip/hip_runtime.h>
#include <hip/hip_bf16.h>

#define HEADS 4
#define CH 64
#define NEG 0.2f
#define LN_EPS 1e-5f

typedef unsigned int u32;
typedef unsigned short u16;

__device__ __forceinline__ float bflo(u32 u) { return __uint_as_float(u << 16); }
__device__ __forceinline__ float bfhi(u32 u) { return __uint_as_float(u & 0xffff0000u); }
__device__ __forceinline__ u16 f2bf(float f) {
    u32 u = __float_as_uint(f);
    u32 r = u + 0x7fffu + ((u >> 16) & 1u);
    return (u16)(r >> 16);
}

// ---------------- CSR build ----------------
__global__ void k_init_cursor(int* cursor, int n) {
    int i = blockIdx.x * blockDim.x + threadIdx.x;
    if (i < n) cursor[i] = 1;  // self loop
}

__global__ void k_count(const int* __restrict__ dst, int* cursor, int E) {
    int stride = gridDim.x * blockDim.x;
    for (int e = blockIdx.x * blockDim.x + threadIdx.x; e < E; e += stride)
        atomicAdd(&cursor[dst[e]], 1);
}

__global__ void k_blocksum(const int* __restrict__ cnt, int* bsum, int n) {
    __shared__ int sh[256];
    int i = blockIdx.x * 256 + threadIdx.x;
    int v = (i < n) ? cnt[i] : 0;
    sh[threadIdx.x] = v;
    __syncthreads();
    for (int off = 128; off; off >>= 1) {
        if (threadIdx.x < off) sh[threadIdx.x] += sh[threadIdx.x + off];
        __syncthreads();
    }
    if (threadIdx.x == 0) bsum[blockIdx.x] = sh[0];
}

__global__ void k_scan_bsum(const int* __restrict__ bsum, int* boff, int nb) {
    __shared__ int sh[1024];
    int t = threadIdx.x;
    int v = (t < nb) ? bsum[t] : 0;
    sh[t] = v;
    __syncthreads();
    for (int off = 1; off < 1024; off <<= 1) {
        int a = (t >= off) ? sh[t - off] : 0;
        __syncthreads();
        sh[t] += a;
        __syncthreads();
    }
    if (t < nb) boff[t] = sh[t] - v;  // exclusive
}

__global__ void k_make_ptr(const int* cnt, const int* __restrict__ boff,
                           int* rowptr, int* cursor, int n) {
    __shared__ int sh[256];
    int t = threadIdx.x;
    int i = blockIdx.x * 256 + t;
    int v = (i < n) ? cnt[i] : 0;
    sh[t] = v;
    __syncthreads();
    for (int off = 1; off < 256; off <<= 1) {
        int a = (t >= off) ? sh[t - off] : 0;
        __syncthreads();
        sh[t] += a;
        __syncthreads();
    }
    int incl = sh[t] + boff[blockIdx.x];
    if (i < n) {
        rowptr[i + 1] = incl;
        cursor[i] = incl - v;
    }
    if (i == 0) rowptr[0] = 0;
}

__global__ void k_fill(const int* __restrict__ src, const int* __restrict__ dst,
                       int* cursor, int* col_src, int E, int n) {
    int stride = gridDim.x * blockDim.x;
    int total = E + n;
    for (int idx = blockIdx.x * blockDim.x + threadIdx.x; idx < total; idx += stride) {
        int s, d;
        if (idx < E) { s = src[idx]; d = dst[idx]; }
        else { s = d = idx - E; }
        int pos = atomicAdd(&cursor[d], 1);
        col_src[pos] = s;
    }
}

// ---------------- per-layer kernels ----------------
// xl = bf16(xin @ Wl), xr = bf16(xin @ Wr).  xin:[n,64] (optionally LN'd on the fly), W:[64,256]
#define GR 16
__global__ void k_gemm2(const float* __restrict__ x, const float* __restrict__ Wl,
                        const float* __restrict__ Wr, u16* __restrict__ xl,
                        u16* __restrict__ xr, int n,
                        const float* __restrict__ musig, const float* __restrict__ lnw,
                        const float* __restrict__ lnb, int useln) {
    __shared__ float xs[GR][64];
    int r0 = blockIdx.x * GR;
    int t = threadIdx.x;  // 0..255 = output col
    float mu = 0.f, rs = 1.f;
    if (useln) { mu = musig[0]; rs = musig[1]; }
    for (int idx = t; idx < GR * 64; idx += 256) {
        int r = idx >> 6, k = idx & 63;
        int rg = r0 + r;
        float xv = (rg < n) ? x[(size_t)rg * 64 + k] : 0.f;
        if (useln) xv = (xv - mu) * rs * lnw[k] + lnb[k];
        xs[r][k] = xv;
    }
    __syncthreads();
    float accl[GR], accr[GR];
#pragma unroll
    for (int r = 0; r < GR; ++r) { accl[r] = 0.f; accr[r] = 0.f; }
    for (int k = 0; k < 64; ++k) {
        float wl = Wl[k * 256 + t];
        float wr = Wr[k * 256 + t];
#pragma unroll
        for (int r = 0; r < GR; ++r) {
            accl[r] = fmaf(xs[r][k], wl, accl[r]);
            accr[r] = fmaf(xs[r][k], wr, accr[r]);
        }
    }
    for (int r = 0; r < GR; ++r) {
        int rg = r0 + r;
        if (rg < n) {
            xl[(size_t)rg * 256 + t] = f2bf(accl[r]);
            xr[(size_t)rg * 256 + t] = f2bf(accr[r]);
        }
    }
}

// Fused GATv2 edge pass: one wave per dst node, all 4 heads.
// Lane l holds channels [4l,4l+4) (head = l/16). Single pass over incoming
// edges: gather xl[src] once, logit via 16-lane butterfly reduce, plain-exp
// softmax accumulated online (logits are O(1), no max subtraction needed).
__global__ void k_fused(const u16* __restrict__ xl, const u16* __restrict__ xr,
                        const int* __restrict__ rowptr, const int* __restrict__ col_src,
                        const float* __restrict__ att, const float* __restrict__ bias,
                        float* __restrict__ y, int n) {
    __shared__ float sh[4][HEADS][64];
    int w = threadIdx.x >> 6;
    int node = blockIdx.x * 4 + w;
    int lane = threadIdx.x & 63;
    if (node >= n) return;
    float a0 = att[lane * 4 + 0], a1 = att[lane * 4 + 1];
    float a2 = att[lane * 4 + 2], a3 = att[lane * 4 + 3];
    uint2 rv = *(const uint2*)(xr + (size_t)node * 256 + lane * 4);
    float r0 = bflo(rv.x), r1 = bfhi(rv.x), r2 = bflo(rv.y), r3 = bfhi(rv.y);
    int start = rowptr[node], end = rowptr[node + 1];
    float acc0 = 0.f, acc1 = 0.f, acc2 = 0.f, acc3 = 0.f, denom = 0.f;
    int s = col_src[start];
    uint2 v = *(const uint2*)(xl + (size_t)s * 256 + lane * 4);
    for (int j = start; j < end; ++j) {
        uint2 vc = v;
        if (j + 1 < end) {
            int sn = col_src[j + 1];
            v = *(const uint2*)(xl + (size_t)sn * 256 + lane * 4);
        }
        float x0 = bflo(vc.x), x1 = bfhi(vc.x), x2 = bflo(vc.y), x3 = bfhi(vc.y);
        float e0 = x0 + r0, e1 = x1 + r1, e2 = x2 + r2, e3 = x3 + r3;
        e0 = fmaxf(e0, NEG * e0); e1 = fmaxf(e1, NEG * e1);
        e2 = fmaxf(e2, NEG * e2); e3 = fmaxf(e3, NEG * e3);
        float e = a0 * e0;
        e = fmaf(a1, e1, e);
        e = fmaf(a2, e2, e);
        e = fmaf(a3, e3, e);
        e += __shfl_xor(e, 1, 64);
        e += __shfl_xor(e, 2, 64);
        e += __shfl_xor(e, 4, 64);
        e += __shfl_xor(e, 8, 64);
        float p = __expf(e);
        denom += p;
        acc0 = fmaf(p, x0, acc0);
        acc1 = fmaf(p, x1, acc1);
        acc2 = fmaf(p, x2, acc2);
        acc3 = fmaf(p, x3, acc3);
    }
    float invd = 1.f / (denom + 1e-16f);
    int cb = (lane & 15) * 4;
    int h = lane >> 4;
    sh[w][h][cb + 0] = acc0 * invd;
    sh[w][h][cb + 1] = acc1 * invd;
    sh[w][h][cb + 2] = acc2 * invd;
    sh[w][h][cb + 3] = acc3 * invd;
    // same-wave LDS write->read: in-order DS pipe, no barrier needed
    float yv = (sh[w][0][lane] + sh[w][1][lane] + sh[w][2][lane] + sh[w][3][lane]) * 0.25f
               + bias[lane];
    y[(size_t)node * 64 + lane] = yv;
}

// ---------------- LayerNorm (graph mode: stats over ALL n*64 values) ----------------
__global__ void k_ln_reduce(const float* __restrict__ y, double* __restrict__ part, int n) {
    double s = 0.0, ss = 0.0;
    int stride = gridDim.x * blockDim.x;
    for (int i = blockIdx.x * blockDim.x + threadIdx.x; i < n; i += stride) {
        double v = (double)y[i];
        s += v;
        ss = fma(v, v, ss);
    }
    __shared__ double shs[256], shss[256];
    int t = threadIdx.x;
    shs[t] = s; shss[t] = ss;
    __syncthreads();
    for (int off = 128; off; off >>= 1) {
        if (t < off) { shs[t] += shs[t + off]; shss[t] += shss[t + off]; }
        __syncthreads();
    }
    if (t == 0) { part[blockIdx.x * 2] = shs[0]; part[blockIdx.x * 2 + 1] = shss[0]; }
}

__global__ void k_ln_final(const double* __restrict__ part, float* musig, int nb, int n) {
    double s = 0.0, ss = 0.0;
    for (int i = threadIdx.x; i < nb; i += blockDim.x) { s += part[i * 2]; ss += part[i * 2 + 1]; }
    __shared__ double shs[512], shss[512];
    shs[threadIdx.x] = s; shss[threadIdx.x] = ss;
    __syncthreads();
    for (int off = 256; off; off >>= 1) {
        if (threadIdx.x < off) { shs[threadIdx.x] += shs[threadIdx.x + off]; shss[threadIdx.x] += shss[threadIdx.x + off]; }
        __syncthreads();
    }
    if (threadIdx.x == 0) {
        double mu = shs[0] / n;
        double var = shss[0] / n - mu * mu;
        musig[0] = (float)mu;
        musig[1] = (float)(1.0 / sqrt(var + (double)LN_EPS));
    }
}

__global__ void k_ln_apply(const float* __restrict__ y, const float* __restrict__ musig,
                           const float* __restrict__ w, const float* __restrict__ b,
                           float* __restrict__ out, int n64) {
    float mu = musig[0], rs = musig[1];
    int stride = gridDim.x * blockDim.x;
    for (int i = blockIdx.x * blockDim.x + threadIdx.x; i < n64; i += stride) {
        int c = i & 63;
        out[i] = (y[i] - mu) * rs * w[c] + b[c];
    }
}

extern "C" void kernel_launch(void* const* d_in, const int* in_sizes, int n_in,
                              void* d_out, int out_size, void* d_ws, size_t ws_size,
                              hipStream_t stream) {
    const float* x0   = (const float*)d_in[0];
    const int*   ei   = (const int*)d_in[1];
    const float* Wl   = (const float*)d_in[2];
    const float* Wr   = (const float*)d_in[3];
    const float* att  = (const float*)d_in[4];
    const float* bias = (const float*)d_in[5];
    const float* lnw  = (const float*)d_in[6];
    const float* lnb  = (const float*)d_in[7];

    const int n  = in_sizes[0] / 64;
    const int E  = in_sizes[1] / 2;
    const int* srcA = ei;
    const int* dstA = ei + E;

    char* p = (char*)d_ws;
    auto alloc = [&](size_t bytes) -> char* {
        char* r = p;
        p += (bytes + 511) & ~((size_t)511);
        return r;
    };
    u16*    xl      = (u16*)alloc((size_t)n * 256 * 2);
    u16*    xr      = (u16*)alloc((size_t)n * 256 * 2);
    float*  ybuf    = (float*)alloc((size_t)n * 64 * 4);
    int*    rowptr  = (int*)alloc((size_t)(n + 1) * 4);
    int*    cursor  = (int*)alloc((size_t)n * 4);
    const int nb    = (n + 255) / 256;
    int*    bsum    = (int*)alloc((size_t)nb * 4);
    int*    boff    = (int*)alloc((size_t)nb * 4);
    int*    col_src = (int*)alloc((size_t)(E + n) * 4);
    double* part    = (double*)alloc(512 * 2 * 8);
    float*  musig   = (float*)alloc(16);

    // ---- CSR build (by dst, self loops appended) ----
    k_init_cursor<<<(n + 255) / 256, 256, 0, stream>>>(cursor, n);
    k_count<<<2048, 256, 0, stream>>>(dstA, cursor, E);
    k_blocksum<<<nb, 256, 0, stream>>>(cursor, bsum, n);
    k_scan_bsum<<<1, 1024, 0, stream>>>(bsum, boff, nb);
    k_make_ptr<<<nb, 256, 0, stream>>>(cursor, boff, rowptr, cursor, n);
    k_fill<<<2048, 256, 0, stream>>>(srcA, dstA, cursor, col_src, E, n);

    // ---- 3 GATv2 layers; LN affine fused into next layer's GEMM staging ----
    for (int l = 0; l < 3; ++l) {
        const float* xin = (l == 0) ? x0 : ybuf;
        k_gemm2<<<(n + GR - 1) / GR, 256, 0, stream>>>(
            xin, Wl + (size_t)l * 64 * 256, Wr + (size_t)l * 64 * 256, xl, xr, n,
            musig, lnw + (l - 1) * 64, lnb + (l - 1) * 64, l > 0 ? 1 : 0);
        k_fused<<<(n + 3) / 4, 256, 0, stream>>>(
            xl, xr, rowptr, col_src, att + l * 256, bias + l * 64, ybuf, n);
        k_ln_reduce<<<512, 256, 0, stream>>>(ybuf, part, n * 64);
        k_ln_final<<<1, 512, 0, stream>>>(part, musig, 512, n * 64);
    }
    k_ln_apply<<<2048, 256, 0, stream>>>(ybuf, musig, lnw + 2 * 64, lnb + 2 * 64,
                                         (float*)d_out, n * 64);
}

// Round 4
// 891.046 us; speedup vs baseline: 2.6519x; 1.4033x over previous
//
#include <hip/hip_runtime.h>
#include <hip/hip_bf16.h>

#define HEADS 4
#define NEG 0.2f
#define LN_EPS 1e-5f

typedef unsigned int u32;
typedef unsigned short u16;

typedef __attribute__((ext_vector_type(8))) short bf16x8;
typedef __attribute__((ext_vector_type(4))) float f32x4;

__device__ __forceinline__ float bflo(u32 u) { return __uint_as_float(u << 16); }
__device__ __forceinline__ float bfhi(u32 u) { return __uint_as_float(u & 0xffff0000u); }
__device__ __forceinline__ u16 f2bf(float f) {
    u32 u = __float_as_uint(f);
    u32 r = u + 0x7fffu + ((u >> 16) & 1u);
    return (u16)(r >> 16);
}

// sum over each 16-lane row via DPP row rotations (no DS pipe, pure VALU)
__device__ __forceinline__ float rowsum16(float e) {
    float t;
    t = __int_as_float(__builtin_amdgcn_update_dpp(0, __float_as_int(e), 0x128, 0xf, 0xf, false));
    e += t;
    t = __int_as_float(__builtin_amdgcn_update_dpp(0, __float_as_int(e), 0x124, 0xf, 0xf, false));
    e += t;
    t = __int_as_float(__builtin_amdgcn_update_dpp(0, __float_as_int(e), 0x122, 0xf, 0xf, false));
    e += t;
    t = __int_as_float(__builtin_amdgcn_update_dpp(0, __float_as_int(e), 0x121, 0xf, 0xf, false));
    e += t;
    return e;
}

// ---------------- CSR build ----------------
__global__ void k_init_cursor(int* cursor, int n) {
    int i = blockIdx.x * blockDim.x + threadIdx.x;
    if (i < n) cursor[i] = 1;  // self loop
}

__global__ void k_count(const int* __restrict__ dst, int* cursor, int E) {
    int stride = gridDim.x * blockDim.x;
    for (int e = blockIdx.x * blockDim.x + threadIdx.x; e < E; e += stride)
        atomicAdd(&cursor[dst[e]], 1);
}

__global__ void k_blocksum(const int* __restrict__ cnt, int* bsum, int n) {
    __shared__ int sh[256];
    int i = blockIdx.x * 256 + threadIdx.x;
    int v = (i < n) ? cnt[i] : 0;
    sh[threadIdx.x] = v;
    __syncthreads();
    for (int off = 128; off; off >>= 1) {
        if (threadIdx.x < off) sh[threadIdx.x] += sh[threadIdx.x + off];
        __syncthreads();
    }
    if (threadIdx.x == 0) bsum[blockIdx.x] = sh[0];
}

__global__ void k_scan_bsum(const int* __restrict__ bsum, int* boff, int nb) {
    __shared__ int sh[1024];
    int t = threadIdx.x;
    int v = (t < nb) ? bsum[t] : 0;
    sh[t] = v;
    __syncthreads();
    for (int off = 1; off < 1024; off <<= 1) {
        int a = (t >= off) ? sh[t - off] : 0;
        __syncthreads();
        sh[t] += a;
        __syncthreads();
    }
    if (t < nb) boff[t] = sh[t] - v;  // exclusive
}

__global__ void k_make_ptr(const int* cnt, const int* __restrict__ boff,
                           int* rowptr, int* cursor, int n) {
    __shared__ int sh[256];
    int t = threadIdx.x;
    int i = blockIdx.x * 256 + t;
    int v = (i < n) ? cnt[i] : 0;
    sh[t] = v;
    __syncthreads();
    for (int off = 1; off < 256; off <<= 1) {
        int a = (t >= off) ? sh[t - off] : 0;
        __syncthreads();
        sh[t] += a;
        __syncthreads();
    }
    int incl = sh[t] + boff[blockIdx.x];
    if (i < n) {
        rowptr[i + 1] = incl;
        cursor[i] = incl - v;
    }
    if (i == 0) rowptr[0] = 0;
}

__global__ void k_fill(const int* __restrict__ src, const int* __restrict__ dst,
                       int* cursor, int* col_src, int E, int n) {
    int stride = gridDim.x * blockDim.x;
    int total = E + n;
    for (int idx = blockIdx.x * blockDim.x + threadIdx.x; idx < total; idx += stride) {
        int s, d;
        if (idx < E) { s = src[idx]; d = dst[idx]; }
        else { s = d = idx - E; }
        int pos = atomicAdd(&cursor[d], 1);
        col_src[pos] = s;
    }
}

// ---------------- MFMA GEMM: xl = bf16(LN(x) @ Wl), xr = bf16(LN(x) @ Wr) ----------------
// Block = 4 waves, 64 rows. Wave w: rows base+w*16. A frag: lane holds
// x[base+w*16+(lane&15)][k], k=(lane>>4)*8+j (j=0..7) and k+32. B frag from W (L2-hot).
// D layout (m89-verified): col=lane&15, row=(lane>>4)*4+reg.
__global__ __launch_bounds__(256) void k_gemm_mfma(
        const float* __restrict__ x, const float* __restrict__ Wl,
        const float* __restrict__ Wr, u16* __restrict__ xl, u16* __restrict__ xr, int n,
        const float* __restrict__ musig, const float* __restrict__ lnw,
        const float* __restrict__ lnb, int useln) {
    int w = threadIdx.x >> 6;
    int lane = threadIdx.x & 63;
    int r = blockIdx.x * 64 + w * 16 + (lane & 15);
    int c0 = (lane >> 4) * 8;

    float mu = 0.f, rs = 1.f;
    if (useln) { mu = musig[0]; rs = musig[1]; }

    float av[16];
    if (r < n) {
        const float* xp = x + (size_t)r * 64;
        float4 t0 = *(const float4*)(xp + c0);
        float4 t1 = *(const float4*)(xp + c0 + 4);
        float4 t2 = *(const float4*)(xp + c0 + 32);
        float4 t3 = *(const float4*)(xp + c0 + 36);
        av[0] = t0.x; av[1] = t0.y; av[2] = t0.z; av[3] = t0.w;
        av[4] = t1.x; av[5] = t1.y; av[6] = t1.z; av[7] = t1.w;
        av[8] = t2.x; av[9] = t2.y; av[10] = t2.z; av[11] = t2.w;
        av[12] = t3.x; av[13] = t3.y; av[14] = t3.z; av[15] = t3.w;
        if (useln) {
#pragma unroll
            for (int j = 0; j < 16; ++j) {
                int k = (j < 8) ? (c0 + j) : (c0 + 24 + j);
                av[j] = (av[j] - mu) * rs * lnw[k] + lnb[k];
            }
        }
    } else {
#pragma unroll
        for (int j = 0; j < 16; ++j) av[j] = 0.f;
    }
    bf16x8 fa0, fa1;
#pragma unroll
    for (int j = 0; j < 8; ++j) {
        fa0[j] = (short)f2bf(av[j]);
        fa1[j] = (short)f2bf(av[8 + j]);
    }

    int nn = lane & 15;
    int kb = (lane >> 4) * 8;
    int row0 = blockIdx.x * 64 + w * 16 + (lane >> 4) * 4;

#pragma unroll 2
    for (int t = 0; t < 32; ++t) {
        const float* W = (t < 16) ? Wl : Wr;
        u16* dst = (t < 16) ? xl : xr;
        int cb = (t & 15) * 16;
        const float* wp = W + (size_t)kb * 256 + cb + nn;
        bf16x8 fb0, fb1;
#pragma unroll
        for (int j = 0; j < 8; ++j) {
            fb0[j] = (short)f2bf(wp[(size_t)j * 256]);
            fb1[j] = (short)f2bf(wp[(size_t)(j + 32) * 256]);
        }
        f32x4 acc = {0.f, 0.f, 0.f, 0.f};
        acc = __builtin_amdgcn_mfma_f32_16x16x32_bf16(fa0, fb0, acc, 0, 0, 0);
        acc = __builtin_amdgcn_mfma_f32_16x16x32_bf16(fa1, fb1, acc, 0, 0, 0);
#pragma unroll
        for (int reg = 0; reg < 4; ++reg) {
            int R = row0 + reg;
            if (R < n) dst[(size_t)R * 256 + cb + nn] = f2bf(acc[reg]);
        }
    }
}

// Fused GATv2 edge pass: one wave per dst node, all 4 heads.
// Lane l = channels [4l,4l+4), head = l/16. DPP row reduce, 2-edge pipeline.
__global__ void k_fused(const u16* __restrict__ xl, const u16* __restrict__ xr,
                        const int* __restrict__ rowptr, const int* __restrict__ col_src,
                        const float* __restrict__ att, const float* __restrict__ bias,
                        float* __restrict__ y, int n) {
    __shared__ float sh[4][HEADS][64];
    int w = threadIdx.x >> 6;
    int node = blockIdx.x * 4 + w;
    int lane = threadIdx.x & 63;
    if (node >= n) return;
    float a0 = att[lane * 4 + 0], a1 = att[lane * 4 + 1];
    float a2 = att[lane * 4 + 2], a3 = att[lane * 4 + 3];
    uint2 rv = *(const uint2*)(xr + (size_t)node * 256 + lane * 4);
    float r0 = bflo(rv.x), r1 = bfhi(rv.x), r2 = bflo(rv.y), r3 = bfhi(rv.y);
    int start = rowptr[node], end = rowptr[node + 1];
    float acc0 = 0.f, acc1 = 0.f, acc2 = 0.f, acc3 = 0.f, denom = 0.f;

    auto PROC = [&](uint2 vc) {
        float x0 = bflo(vc.x), x1 = bfhi(vc.x), x2 = bflo(vc.y), x3 = bfhi(vc.y);
        float e0 = x0 + r0, e1 = x1 + r1, e2 = x2 + r2, e3 = x3 + r3;
        e0 = fmaxf(e0, NEG * e0); e1 = fmaxf(e1, NEG * e1);
        e2 = fmaxf(e2, NEG * e2); e3 = fmaxf(e3, NEG * e3);
        float e = a0 * e0;
        e = fmaf(a1, e1, e);
        e = fmaf(a2, e2, e);
        e = fmaf(a3, e3, e);
        e = rowsum16(e);
        float p = __expf(e);
        denom += p;
        acc0 = fmaf(p, x0, acc0);
        acc1 = fmaf(p, x1, acc1);
        acc2 = fmaf(p, x2, acc2);
        acc3 = fmaf(p, x3, acc3);
    };

    const size_t lo4 = (size_t)lane * 4;
    uint2 va, vb;
    va = *(const uint2*)(xl + (size_t)col_src[start] * 256 + lo4);
    if (start + 1 < end) vb = *(const uint2*)(xl + (size_t)col_src[start + 1] * 256 + lo4);
    int j = start;
    for (; j + 2 < end; j += 2) {
        uint2 c0 = va, c1 = vb;
        va = *(const uint2*)(xl + (size_t)col_src[j + 2] * 256 + lo4);
        if (j + 3 < end) vb = *(const uint2*)(xl + (size_t)col_src[j + 3] * 256 + lo4);
        PROC(c0);
        PROC(c1);
    }
    PROC(va);
    if (end - j == 2) PROC(vb);

    float invd = 1.f / (denom + 1e-16f);
    int cb = (lane & 15) * 4;
    int h = lane >> 4;
    sh[w][h][cb + 0] = acc0 * invd;
    sh[w][h][cb + 1] = acc1 * invd;
    sh[w][h][cb + 2] = acc2 * invd;
    sh[w][h][cb + 3] = acc3 * invd;
    // same-wave LDS write->read: in-order DS pipe, no barrier needed
    float yv = (sh[w][0][lane] + sh[w][1][lane] + sh[w][2][lane] + sh[w][3][lane]) * 0.25f
               + bias[lane];
    y[(size_t)node * 64 + lane] = yv;
}

// ---------------- LayerNorm (graph mode: stats over ALL n*64 values) ----------------
__global__ void k_ln_reduce(const float* __restrict__ y, double* __restrict__ part, int n) {
    double s = 0.0, ss = 0.0;
    int stride = gridDim.x * blockDim.x;
    for (int i = blockIdx.x * blockDim.x + threadIdx.x; i < n; i += stride) {
        double v = (double)y[i];
        s += v;
        ss = fma(v, v, ss);
    }
    __shared__ double shs[256], shss[256];
    int t = threadIdx.x;
    shs[t] = s; shss[t] = ss;
    __syncthreads();
    for (int off = 128; off; off >>= 1) {
        if (t < off) { shs[t] += shs[t + off]; shss[t] += shss[t + off]; }
        __syncthreads();
    }
    if (t == 0) { part[blockIdx.x * 2] = shs[0]; part[blockIdx.x * 2 + 1] = shss[0]; }
}

__global__ void k_ln_final(const double* __restrict__ part, float* musig, int nb, int n) {
    double s = 0.0, ss = 0.0;
    for (int i = threadIdx.x; i < nb; i += blockDim.x) { s += part[i * 2]; ss += part[i * 2 + 1]; }
    __shared__ double shs[512], shss[512];
    shs[threadIdx.x] = s; shss[threadIdx.x] = ss;
    __syncthreads();
    for (int off = 256; off; off >>= 1) {
        if (threadIdx.x < off) { shs[threadIdx.x] += shs[threadIdx.x + off]; shss[threadIdx.x] += shss[threadIdx.x + off]; }
        __syncthreads();
    }
    if (threadIdx.x == 0) {
        double mu = shs[0] / n;
        double var = shss[0] / n - mu * mu;
        musig[0] = (float)mu;
        musig[1] = (float)(1.0 / sqrt(var + (double)LN_EPS));
    }
}

__global__ void k_ln_apply(const float* __restrict__ y, const float* __restrict__ musig,
                           const float* __restrict__ w, const float* __restrict__ b,
                           float* __restrict__ out, int n64) {
    float mu = musig[0], rs = musig[1];
    int stride = gridDim.x * blockDim.x;
    for (int i = blockIdx.x * blockDim.x + threadIdx.x; i < n64; i += stride) {
        int c = i & 63;
        out[i] = (y[i] - mu) * rs * w[c] + b[c];
    }
}

extern "C" void kernel_launch(void* const* d_in, const int* in_sizes, int n_in,
                              void* d_out, int out_size, void* d_ws, size_t ws_size,
                              hipStream_t stream) {
    const float* x0   = (const float*)d_in[0];
    const int*   ei   = (const int*)d_in[1];
    const float* Wl   = (const float*)d_in[2];
    const float* Wr   = (const float*)d_in[3];
    const float* att  = (const float*)d_in[4];
    const float* bias = (const float*)d_in[5];
    const float* lnw  = (const float*)d_in[6];
    const float* lnb  = (const float*)d_in[7];

    const int n  = in_sizes[0] / 64;
    const int E  = in_sizes[1] / 2;
    const int* srcA = ei;
    const int* dstA = ei + E;

    char* p = (char*)d_ws;
    auto alloc = [&](size_t bytes) -> char* {
        char* r = p;
        p += (bytes + 511) & ~((size_t)511);
        return r;
    };
    u16*    xl      = (u16*)alloc((size_t)n * 256 * 2);
    u16*    xr      = (u16*)alloc((size_t)n * 256 * 2);
    float*  ybuf    = (float*)alloc((size_t)n * 64 * 4);
    int*    rowptr  = (int*)alloc((size_t)(n + 1) * 4);
    int*    cursor  = (int*)alloc((size_t)n * 4);
    const int nb    = (n + 255) / 256;
    int*    bsum    = (int*)alloc((size_t)nb * 4);
    int*    boff    = (int*)alloc((size_t)nb * 4);
    int*    col_src = (int*)alloc((size_t)(E + n) * 4);
    double* part    = (double*)alloc(512 * 2 * 8);
    float*  musig   = (float*)alloc(16);

    // ---- CSR build (by dst, self loops appended) ----
    k_init_cursor<<<(n + 255) / 256, 256, 0, stream>>>(cursor, n);
    k_count<<<2048, 256, 0, stream>>>(dstA, cursor, E);
    k_blocksum<<<nb, 256, 0, stream>>>(cursor, bsum, n);
    k_scan_bsum<<<1, 1024, 0, stream>>>(bsum, boff, nb);
    k_make_ptr<<<nb, 256, 0, stream>>>(cursor, boff, rowptr, cursor, n);
    k_fill<<<2048, 256, 0, stream>>>(srcA, dstA, cursor, col_src, E, n);

    // ---- 3 GATv2 layers; LN affine fused into next layer's GEMM staging ----
    for (int l = 0; l < 3; ++l) {
        const float* xin = (l == 0) ? x0 : ybuf;
        k_gemm_mfma<<<(n + 63) / 64, 256, 0, stream>>>(
            xin, Wl + (size_t)l * 64 * 256, Wr + (size_t)l * 64 * 256, xl, xr, n,
            musig, lnw + (l - 1) * 64, lnb + (l - 1) * 64, l > 0 ? 1 : 0);
        k_fused<<<(n + 3) / 4, 256, 0, stream>>>(
            xl, xr, rowptr, col_src, att + l * 256, bias + l * 64, ybuf, n);
        k_ln_reduce<<<512, 256, 0, stream>>>(ybuf, part, n * 64);
        k_ln_final<<<1, 512, 0, stream>>>(part, musig, 512, n * 64);
    }
    k_ln_apply<<<2048, 256, 0, stream>>>(ybuf, musig, lnw + 2 * 64, lnb + 2 * 64,
                                         (float*)d_out, n * 64);
}

// Round 6
// 736.304 us; speedup vs baseline: 3.2093x; 1.2102x over previous
//
#include <hip/hip_runtime.h>
#include <hip/hip_bf16.h>

#define HEADS 4
#define NEG 0.2f
#define LN_EPS 1e-5f
#define LOG2E 1.4426950408889634f

typedef unsigned int u32;
typedef unsigned short u16;

typedef __attribute__((ext_vector_type(8))) short bf16x8;
typedef __attribute__((ext_vector_type(4))) float f32x4;

__device__ __forceinline__ float bflo(u32 u) { return __uint_as_float(u << 16); }
__device__ __forceinline__ float bfhi(u32 u) { return __uint_as_float(u & 0xffff0000u); }
__device__ __forceinline__ u16 f2bf(float f) {
    u32 u = __float_as_uint(f);
    u32 r = u + 0x7fffu + ((u >> 16) & 1u);
    return (u16)(r >> 16);
}

template <int CTRL>
__device__ __forceinline__ float dppadd(float e) {
    float t = __int_as_float(
        __builtin_amdgcn_update_dpp(0, __float_as_int(e), CTRL, 0xf, 0xf, false));
    return e + t;
}
// sum over each 8-lane group: quad xor1, quad xor2, row_half_mirror
__device__ __forceinline__ float redsum8(float e) {
    e = dppadd<0xB1>(e);   // quad_perm [1,0,3,2]
    e = dppadd<0x4E>(e);   // quad_perm [2,3,0,1]
    e = dppadd<0x141>(e);  // row_half_mirror
    return e;
}

// ---------------- CSR build ----------------
__global__ void k_init(int* cursor, int n, float* buckets) {
    int i = blockIdx.x * blockDim.x + threadIdx.x;
    if (i < n) cursor[i] = 1;  // self loop
    if (i < 1024) buckets[i] = 0.f;
}

__global__ void k_count(const int* __restrict__ dst, int* cursor, int E) {
    int stride = gridDim.x * blockDim.x;
    for (int e = blockIdx.x * blockDim.x + threadIdx.x; e < E; e += stride)
        atomicAdd(&cursor[dst[e]], 1);
}

__global__ void k_blocksum(const int* __restrict__ cnt, int* bsum, int n) {
    __shared__ int sh[256];
    int i = blockIdx.x * 256 + threadIdx.x;
    int v = (i < n) ? cnt[i] : 0;
    sh[threadIdx.x] = v;
    __syncthreads();
    for (int off = 128; off; off >>= 1) {
        if (threadIdx.x < off) sh[threadIdx.x] += sh[threadIdx.x + off];
        __syncthreads();
    }
    if (threadIdx.x == 0) bsum[blockIdx.x] = sh[0];
}

__global__ void k_scan_bsum(const int* __restrict__ bsum, int* boff, int nb) {
    __shared__ int sh[1024];
    int t = threadIdx.x;
    int v = (t < nb) ? bsum[t] : 0;
    sh[t] = v;
    __syncthreads();
    for (int off = 1; off < 1024; off <<= 1) {
        int a = (t >= off) ? sh[t - off] : 0;
        __syncthreads();
        sh[t] += a;
        __syncthreads();
    }
    if (t < nb) boff[t] = sh[t] - v;  // exclusive
}

__global__ void k_make_ptr(const int* cnt, const int* __restrict__ boff,
                           int* rowptr, int* cursor, int n) {
    __shared__ int sh[256];
    int t = threadIdx.x;
    int i = blockIdx.x * 256 + t;
    int v = (i < n) ? cnt[i] : 0;
    sh[t] = v;
    __syncthreads();
    for (int off = 1; off < 256; off <<= 1) {
        int a = (t >= off) ? sh[t - off] : 0;
        __syncthreads();
        sh[t] += a;
        __syncthreads();
    }
    int incl = sh[t] + boff[blockIdx.x];
    if (i < n) {
        rowptr[i + 1] = incl;
        cursor[i] = incl - v;
    }
    if (i == 0) rowptr[0] = 0;
}

__global__ void k_fill(const int* __restrict__ src, const int* __restrict__ dst,
                       int* cursor, int* col_src, int E, int n) {
    int stride = gridDim.x * blockDim.x;
    int total = E + n;
    for (int idx = blockIdx.x * blockDim.x + threadIdx.x; idx < total; idx += stride) {
        int s, d;
        if (idx < E) { s = src[idx]; d = dst[idx]; }
        else { s = d = idx - E; }
        int pos = atomicAdd(&cursor[d], 1);
        col_src[pos] = s;
    }
}

// ---------------- W -> bf16 MFMA-fragment layout ----------------
// wt[mat][t][kq][nn][half][j]  (6,16,4,16,2,8); value = bf16(W[kq*8+half*32+j][t*16+nn])
__global__ void k_prep_w(const float* __restrict__ Wl, const float* __restrict__ Wr,
                         u16* __restrict__ wt) {
    int idx = blockIdx.x * 256 + threadIdx.x;
    if (idx >= 6 * 16384) return;
    int mat = idx >> 14;
    int rem = idx & 16383;
    int t = rem >> 10;
    int kq = (rem >> 8) & 3;
    int nn = (rem >> 4) & 15;
    int half = (rem >> 3) & 1;
    int j = rem & 7;
    int c = t * 16 + nn;
    int k = kq * 8 + half * 32 + j;
    const float* W = (mat < 3) ? (Wl + (size_t)mat * 16384) : (Wr + (size_t)(mat - 3) * 16384);
    wt[idx] = f2bf(W[k * 256 + c]);
}

// ---------------- MFMA GEMM: xl = bf16(LN(x) @ Wl), xr = bf16(LN(x) @ Wr) ----------------
// Block = 4 waves, 64 rows. A frag: lane holds x[base+w*16+(lane&15)][k],
// k=(lane>>4)*8+j and k+32. B frags preconverted (k_prep_w). D: col=lane&15,
// row=(lane>>4)*4+reg (m89-verified mapping).
__global__ __launch_bounds__(256) void k_gemm_mfma(
        const float* __restrict__ x, const u16* __restrict__ wtl,
        const u16* __restrict__ wtr, u16* __restrict__ xl, u16* __restrict__ xr, int n,
        const float* __restrict__ musig, const float* __restrict__ lnw,
        const float* __restrict__ lnb, int useln) {
    int w = threadIdx.x >> 6;
    int lane = threadIdx.x & 63;
    int r = blockIdx.x * 64 + w * 16 + (lane & 15);
    int c0 = (lane >> 4) * 8;

    float mu = 0.f, rs = 1.f;
    if (useln) { mu = musig[0]; rs = musig[1]; }

    float av[16];
    if (r < n) {
        const float* xp = x + (size_t)r * 64;
        float4 t0 = *(const float4*)(xp + c0);
        float4 t1 = *(const float4*)(xp + c0 + 4);
        float4 t2 = *(const float4*)(xp + c0 + 32);
        float4 t3 = *(const float4*)(xp + c0 + 36);
        av[0] = t0.x; av[1] = t0.y; av[2] = t0.z; av[3] = t0.w;
        av[4] = t1.x; av[5] = t1.y; av[6] = t1.z; av[7] = t1.w;
        av[8] = t2.x; av[9] = t2.y; av[10] = t2.z; av[11] = t2.w;
        av[12] = t3.x; av[13] = t3.y; av[14] = t3.z; av[15] = t3.w;
        if (useln) {
            float4 w0 = *(const float4*)(lnw + c0);
            float4 w1 = *(const float4*)(lnw + c0 + 4);
            float4 w2 = *(const float4*)(lnw + c0 + 32);
            float4 w3 = *(const float4*)(lnw + c0 + 36);
            float4 b0 = *(const float4*)(lnb + c0);
            float4 b1 = *(const float4*)(lnb + c0 + 4);
            float4 b2 = *(const float4*)(lnb + c0 + 32);
            float4 b3 = *(const float4*)(lnb + c0 + 36);
            float lw[16] = {w0.x,w0.y,w0.z,w0.w, w1.x,w1.y,w1.z,w1.w,
                            w2.x,w2.y,w2.z,w2.w, w3.x,w3.y,w3.z,w3.w};
            float lb[16] = {b0.x,b0.y,b0.z,b0.w, b1.x,b1.y,b1.z,b1.w,
                            b2.x,b2.y,b2.z,b2.w, b3.x,b3.y,b3.z,b3.w};
#pragma unroll
            for (int j = 0; j < 16; ++j) av[j] = (av[j] - mu) * rs * lw[j] + lb[j];
        }
    } else {
#pragma unroll
        for (int j = 0; j < 16; ++j) av[j] = 0.f;
    }
    bf16x8 fa0, fa1;
#pragma unroll
    for (int j = 0; j < 8; ++j) {
        fa0[j] = (short)f2bf(av[j]);
        fa1[j] = (short)f2bf(av[8 + j]);
    }

    int nn = lane & 15;
    int kq = lane >> 4;
    int row0 = blockIdx.x * 64 + w * 16 + kq * 4;
    int fragoff = kq * 256 + nn * 16;

#pragma unroll 4
    for (int t = 0; t < 16; ++t) {
        const u16* wp = wtl + t * 1024 + fragoff;
        bf16x8 fb0 = *(const bf16x8*)(wp);
        bf16x8 fb1 = *(const bf16x8*)(wp + 8);
        f32x4 acc = {0.f, 0.f, 0.f, 0.f};
        acc = __builtin_amdgcn_mfma_f32_16x16x32_bf16(fa0, fb0, acc, 0, 0, 0);
        acc = __builtin_amdgcn_mfma_f32_16x16x32_bf16(fa1, fb1, acc, 0, 0, 0);
        int cb = t * 16;
#pragma unroll
        for (int reg = 0; reg < 4; ++reg) {
            int R = row0 + reg;
            if (R < n) xl[(size_t)R * 256 + cb + nn] = f2bf(acc[reg]);
        }
    }
#pragma unroll 4
    for (int t = 0; t < 16; ++t) {
        const u16* wp = wtr + t * 1024 + fragoff;
        bf16x8 fb0 = *(const bf16x8*)(wp);
        bf16x8 fb1 = *(const bf16x8*)(wp + 8);
        f32x4 acc = {0.f, 0.f, 0.f, 0.f};
        acc = __builtin_amdgcn_mfma_f32_16x16x32_bf16(fa0, fb0, acc, 0, 0, 0);
        acc = __builtin_amdgcn_mfma_f32_16x16x32_bf16(fa1, fb1, acc, 0, 0, 0);
        int cb = t * 16;
#pragma unroll
        for (int reg = 0; reg < 4; ++reg) {
            int R = row0 + reg;
            if (R < n) xr[(size_t)R * 256 + cb + nn] = f2bf(acc[reg]);
        }
    }
}

// ---------------- Fused GATv2 edge pass ----------------
// Wave per dst node; lane layout: half = lane>>5 (edge stream), l32 = lane&31,
// 8 channels g = l32*8+j, head = l32>>3. Two edges per iteration, 3-step DPP
// logit reduce, att pre-scaled by log2e so p = exp2(e). LN stats fused
// (block partials -> 512-way bucketed f32 atomics).
__global__ __launch_bounds__(256) void k_fused(
        const u16* __restrict__ xl, const u16* __restrict__ xr,
        const int* __restrict__ rowptr, const int* __restrict__ col_src,
        const float* __restrict__ att, const float* __restrict__ bias,
        float* __restrict__ y, float* __restrict__ buckets, int n) {
    __shared__ float shv[4][HEADS][64];
    __shared__ float redS[4], redQ[4];
    int w = threadIdx.x >> 6;
    int node = blockIdx.x * 4 + w;
    int lane = threadIdx.x & 63;
    int half = lane >> 5;
    int l32 = lane & 31;
    bool act = node < n;
    float yv = 0.f;

    if (act) {
        // att (pre-scaled) and xr for this lane's 8 channels
        float a[8], rr[8];
        {
            const float* ap = att + l32 * 8;
            float4 a0 = *(const float4*)(ap);
            float4 a1 = *(const float4*)(ap + 4);
            a[0] = a0.x * LOG2E; a[1] = a0.y * LOG2E; a[2] = a0.z * LOG2E; a[3] = a0.w * LOG2E;
            a[4] = a1.x * LOG2E; a[5] = a1.y * LOG2E; a[6] = a1.z * LOG2E; a[7] = a1.w * LOG2E;
            uint4 rv = *(const uint4*)(xr + (size_t)node * 256 + l32 * 8);
            rr[0] = bflo(rv.x); rr[1] = bfhi(rv.x);
            rr[2] = bflo(rv.y); rr[3] = bfhi(rv.y);
            rr[4] = bflo(rv.z); rr[5] = bfhi(rv.z);
            rr[6] = bflo(rv.w); rr[7] = bfhi(rv.w);
        }
        int start = rowptr[node], end = rowptr[node + 1];
        int d = end - start;
        int iters = (d + 1) >> 1;
        float acc[8] = {0.f, 0.f, 0.f, 0.f, 0.f, 0.f, 0.f, 0.f};
        float denom = 0.f;
        int j = start + half;
        const size_t co = (size_t)l32 * 8;
        uint4 v;
        {
            int jc = min(j, end - 1);
            int s = col_src[jc];
            v = *(const uint4*)(xl + (size_t)s * 256 + co);
        }
        for (int i = 0; i < iters; ++i) {
            uint4 vc = v;
            bool valid = j < end;
            int jn = j + 2;
            if (i + 1 < iters) {
                int jnc = min(jn, end - 1);
                int sn = col_src[jnc];
                v = *(const uint4*)(xl + (size_t)sn * 256 + co);
            }
            float x0 = bflo(vc.x), x1 = bfhi(vc.x), x2 = bflo(vc.y), x3 = bfhi(vc.y);
            float x4 = bflo(vc.z), x5 = bfhi(vc.z), x6 = bflo(vc.w), x7 = bfhi(vc.w);
            float e0 = x0 + rr[0], e1 = x1 + rr[1], e2 = x2 + rr[2], e3 = x3 + rr[3];
            float e4 = x4 + rr[4], e5 = x5 + rr[5], e6 = x6 + rr[6], e7 = x7 + rr[7];
            e0 = fmaxf(e0, NEG * e0); e1 = fmaxf(e1, NEG * e1);
            e2 = fmaxf(e2, NEG * e2); e3 = fmaxf(e3, NEG * e3);
            e4 = fmaxf(e4, NEG * e4); e5 = fmaxf(e5, NEG * e5);
            e6 = fmaxf(e6, NEG * e6); e7 = fmaxf(e7, NEG * e7);
            float e = a[0] * e0;
            e = fmaf(a[1], e1, e);
            e = fmaf(a[2], e2, e);
            e = fmaf(a[3], e3, e);
            e = fmaf(a[4], e4, e);
            e = fmaf(a[5], e5, e);
            e = fmaf(a[6], e6, e);
            e = fmaf(a[7], e7, e);
            e = redsum8(e);
            float p = exp2f(e);
            p = valid ? p : 0.f;
            denom += p;
            acc[0] = fmaf(p, x0, acc[0]);
            acc[1] = fmaf(p, x1, acc[1]);
            acc[2] = fmaf(p, x2, acc[2]);
            acc[3] = fmaf(p, x3, acc[3]);
            acc[4] = fmaf(p, x4, acc[4]);
            acc[5] = fmaf(p, x5, acc[5]);
            acc[6] = fmaf(p, x6, acc[6]);
            acc[7] = fmaf(p, x7, acc[7]);
            j = jn;
        }
        // fold the two edge streams
#pragma unroll
        for (int q = 0; q < 8; ++q) acc[q] += __shfl_xor(acc[q], 32, 64);
        denom += __shfl_xor(denom, 32, 64);
        float invd = 0.25f / (denom + 1e-16f);
        if (half == 0) {
            int h = l32 >> 3;
            int cb = (l32 & 7) * 8;
#pragma unroll
            for (int q = 0; q < 8; ++q) shv[w][h][cb + q] = acc[q] * invd;
        }
        // same-wave DS write->read: in-order, no barrier needed
        yv = shv[w][0][lane] + shv[w][1][lane] + shv[w][2][lane] + shv[w][3][lane]
             + bias[lane];
        y[(size_t)node * 64 + lane] = yv;
    }

    // fused LN statistics: wave reduce -> block reduce -> bucketed atomics
    float s1 = yv, s2 = yv * yv;
#pragma unroll
    for (int off = 32; off; off >>= 1) {
        s1 += __shfl_xor(s1, off, 64);
        s2 += __shfl_xor(s2, off, 64);
    }
    if (lane == 0) { redS[w] = act ? s1 : 0.f; redQ[w] = act ? s2 : 0.f; }
    __syncthreads();
    if (threadIdx.x == 0) {
        float bs = redS[0] + redS[1] + redS[2] + redS[3];
        float bq = redQ[0] + redQ[1] + redQ[2] + redQ[3];
        int b = blockIdx.x & 511;
        atomicAdd(&buckets[b], bs);
        atomicAdd(&buckets[512 + b], bq);
    }
}

// ---------------- LayerNorm finalize: buckets -> musig, re-zero buckets ----------------
__global__ void k_ln_final(float* __restrict__ buckets, float* musig, int n64) {
    int t = threadIdx.x;  // 512
    double s = (double)buckets[t];
    double q = (double)buckets[512 + t];
    __shared__ double shs[512], shq[512];
    shs[t] = s; shq[t] = q;
    __syncthreads();
    for (int off = 256; off; off >>= 1) {
        if (t < off) { shs[t] += shs[t + off]; shq[t] += shq[t + off]; }
        __syncthreads();
    }
    if (t == 0) {
        double mu = shs[0] / n64;
        double var = shq[0] / n64 - mu * mu;
        musig[0] = (float)mu;
        musig[1] = (float)(1.0 / sqrt(var + (double)LN_EPS));
    }
    buckets[t] = 0.f;
    buckets[512 + t] = 0.f;
}

__global__ void k_ln_apply(const float* __restrict__ y, const float* __restrict__ musig,
                           const float* __restrict__ w, const float* __restrict__ b,
                           float* __restrict__ out, int n64) {
    float mu = musig[0], rs = musig[1];
    int stride = gridDim.x * blockDim.x;
    for (int i = blockIdx.x * blockDim.x + threadIdx.x; i < n64; i += stride) {
        int c = i & 63;
        out[i] = (y[i] - mu) * rs * w[c] + b[c];
    }
}

extern "C" void kernel_launch(void* const* d_in, const int* in_sizes, int n_in,
                              void* d_out, int out_size, void* d_ws, size_t ws_size,
                              hipStream_t stream) {
    const float* x0   = (const float*)d_in[0];
    const int*   ei   = (const int*)d_in[1];
    const float* Wl   = (const float*)d_in[2];
    const float* Wr   = (const float*)d_in[3];
    const float* att  = (const float*)d_in[4];
    const float* bias = (const float*)d_in[5];
    const float* lnw  = (const float*)d_in[6];
    const float* lnb  = (const float*)d_in[7];

    const int n  = in_sizes[0] / 64;
    const int E  = in_sizes[1] / 2;
    const int* srcA = ei;
    const int* dstA = ei + E;

    char* p = (char*)d_ws;
    auto alloc = [&](size_t bytes) -> char* {
        char* r = p;
        p += (bytes + 511) & ~((size_t)511);
        return r;
    };
    u16*    xl      = (u16*)alloc((size_t)n * 256 * 2);
    u16*    xr      = (u16*)alloc((size_t)n * 256 * 2);
    float*  ybuf    = (float*)alloc((size_t)n * 64 * 4);
    int*    rowptr  = (int*)alloc((size_t)(n + 1) * 4);
    int*    cursor  = (int*)alloc((size_t)n * 4);
    const int nb    = (n + 255) / 256;
    int*    bsum    = (int*)alloc((size_t)nb * 4);
    int*    boff    = (int*)alloc((size_t)nb * 4);
    int*    col_src = (int*)alloc((size_t)(E + n) * 4);
    u16*    wt      = (u16*)alloc((size_t)6 * 16384 * 2);
    float*  buckets = (float*)alloc(1024 * 4);
    float*  musig   = (float*)alloc(16);

    // ---- CSR build (by dst, self loops appended) + W fragment prep ----
    k_init<<<(n + 255) / 256, 256, 0, stream>>>(cursor, n, buckets);
    k_count<<<2048, 256, 0, stream>>>(dstA, cursor, E);
    k_blocksum<<<nb, 256, 0, stream>>>(cursor, bsum, n);
    k_scan_bsum<<<1, 1024, 0, stream>>>(bsum, boff, nb);
    k_make_ptr<<<nb, 256, 0, stream>>>(cursor, boff, rowptr, cursor, n);
    k_fill<<<2048, 256, 0, stream>>>(srcA, dstA, cursor, col_src, E, n);
    k_prep_w<<<(6 * 16384 + 255) / 256, 256, 0, stream>>>(Wl, Wr, wt);

    // ---- 3 GATv2 layers; LN affine fused into next layer's GEMM staging ----
    for (int l = 0; l < 3; ++l) {
        const float* xin = (l == 0) ? x0 : ybuf;
        k_gemm_mfma<<<(n + 63) / 64, 256, 0, stream>>>(
            xin, wt + (size_t)l * 16384, wt + (size_t)(3 + l) * 16384, xl, xr, n,
            musig, lnw + (l - 1) * 64, lnb + (l - 1) * 64, l > 0 ? 1 : 0);
        k_fused<<<(n + 3) / 4, 256, 0, stream>>>(
            xl, xr, rowptr, col_src, att + l * 256, bias + l * 64, ybuf, buckets, n);
        k_ln_final<<<1, 512, 0, stream>>>(buckets, musig, n * 64);
    }
    k_ln_apply<<<2048, 256, 0, stream>>>(ybuf, musig, lnw + 2 * 64, lnb + 2 * 64,
                                         (float*)d_out, n * 64);
}